// Round 2
// baseline (498.311 us; speedup 1.0000x reference)
//
#include <hip/hip_runtime.h>
#include <hip/hip_bf16.h>
#include <stdint.h>

#define B_SZ   128
#define D_SZ   3072
#define N_SZ   20000
#define NPAD   20480   // 313*64 score tiles (20032) < NPAD; 20 drift K-chunks * 1024
#define BN     (B_SZ * NPAD)     // 2621440 elems
#define BD     (B_SZ * D_SZ)     // 393216 elems
#define KC_S   4                 // scores K-chunks (768 each)
#define KC_D   20                // drift K-chunks (1024 each)

typedef __attribute__((ext_vector_type(8))) short          short8;
typedef __attribute__((ext_vector_type(4))) float          f32x4;
typedef __attribute__((ext_vector_type(4))) unsigned short u16x4;
typedef __attribute__((ext_vector_type(2))) unsigned int   uint2v;

__device__ __forceinline__ unsigned short f2bf(float f) {
    unsigned u = __float_as_uint(f);
    u += 0x7FFFu + ((u >> 16) & 1u);   // round-to-nearest-even
    return (unsigned short)(u >> 16);
}
__device__ __forceinline__ float bf2f(unsigned short h) {
    return __uint_as_float(((unsigned)h) << 16);
}
// order-preserving float<->uint key for atomicMax over signed floats
__device__ __forceinline__ unsigned fkey_enc(float f) {
    unsigned b = __float_as_uint(f);
    return (b & 0x80000000u) ? ~b : (b | 0x80000000u);
}
__device__ __forceinline__ float fkey_dec(unsigned u) {
    return __uint_as_float((u & 0x80000000u) ? (u ^ 0x80000000u) : ~u);
}

__device__ __forceinline__ void gl_lds16(const void* g, void* l) {
    __builtin_amdgcn_global_load_lds(
        (const __attribute__((address_space(1))) void*)g,
        (__attribute__((address_space(3))) void*)l, 16, 0, 0);
}

// bank swizzle: 16B slot for (row r, k-quarter q) is q ^ ((r>>1)&3) -> 2-way
// aliasing only (free, m136); permutes within a 64B row so global coalescing
// of the staging loads is unchanged.
__device__ __forceinline__ int swz(int r, int q) { return q ^ ((r >> 1) & 3); }

// ---------------- zero G2 + Mkey + L (20736 floats, contiguous) ------------
__global__ __launch_bounds__(256) void zero_small(float* __restrict__ p)
{
    p[blockIdx.x * 256 + threadIdx.x] = 0.f;   // grid 81: 81*256 = 20736
}

// ---------------- split x into bf16 hi/lo ----------------
__global__ __launch_bounds__(256) void prep_x(const float* __restrict__ x,
                                              unsigned short* __restrict__ xhi,
                                              unsigned short* __restrict__ xlo)
{
    int i = blockIdx.x * 256 + threadIdx.x;     // exactly 128*3072
    float v = x[i];
    unsigned short h = f2bf(v);
    xhi[i] = h;
    xlo[i] = f2bf(v - bf2f(h));
}

// ---------------- scores: XG_part[kc][b][n] = partial x.g (plain stores) ----
// grid = 313 n-tiles * 4 K-chunks = 1252 blocks. Tile M=128 x N=64, K 768.
// Also emits Gh = bf16(gt) (each gt element visited exactly once across the
// grid) so drift can read half the bytes and skip fp32->bf16 conversion.
// split-precision: acc = xhi*ghi + xhi*glo + xlo*ghi  (fp32-accurate dot)
__global__ __launch_bounds__(256) void scores_kernel(
        const float* __restrict__ gt,
        const unsigned short* __restrict__ xhi,
        const unsigned short* __restrict__ xlo,
        float* __restrict__ XG_part,
        float* __restrict__ G2,
        unsigned short* __restrict__ Gh)
{
    __shared__ __align__(16) unsigned short Xhi_t[128 * 32];
    __shared__ __align__(16) unsigned short Xlo_t[128 * 32];
    __shared__ __align__(16) unsigned short Ghi_t[64 * 32];
    __shared__ __align__(16) unsigned short Glo_t[64 * 32];

    const int tid   = threadIdx.x;
    const int kc    = blockIdx.x & 3;        // K-chunk (4 x 768)
    const int nt    = blockIdx.x >> 2;       // n-tile (313)
    const int nbase = nt * 64;
    const int kcb   = kc * 768;

    const int lane = tid & 63;
    const int wave = tid >> 6;
    const int mh = wave & 1;      // M half (64 rows)
    const int nh = wave >> 1;     // N half (32 cols)
    const int lm = lane & 15;
    const int qd = lane >> 4;

    // G staging map: thread -> (row gn of 64, k-quarter gq of 4 -> 8 elems)
    const int gn = tid >> 2;
    const int gq = tid & 3;
    const int ng0 = nbase + gn;              // unclamped (for guards)
    int grow = ng0 > N_SZ - 1 ? N_SZ - 1 : ng0;
    const float* gp0 = gt + (size_t)grow * D_SZ + kcb + gq * 8;
    unsigned short* ghp0 = Gh + (size_t)ng0 * D_SZ + kcb + gq * 8;
    const int gwr = gn * 32 + swz(gn, gq) * 8;   // swizzled LDS slot (elems)

    // X staging (global_load_lds, lane-order dest): lane's implicit LDS slot
    // is (r = o>>6, j = (o>>4)&3); fetch the global k-group j^f(r) so readers
    // can use the same swizzle.
    int xsrc[2], xdst[2];
    #pragma unroll
    for (int i = 0; i < 2; i++) {
        int o = (i * 256 + tid) * 16;
        int r = o >> 6;
        int j = (o >> 4) & 3;
        xdst[i] = o;
        xsrc[i] = r * D_SZ + kcb + swz(r, j) * 8;
    }

    float g2acc = 0.0f;

    f32x4 acc[4][2];
    #pragma unroll
    for (int i = 0; i < 4; i++)
        #pragma unroll
        for (int j = 0; j < 2; j++)
            acc[i][j] = (f32x4){0.f, 0.f, 0.f, 0.f};

    for (int k0 = 0; k0 < 768; k0 += 32) {
        // stage X hi/lo via async global->LDS
        #pragma unroll
        for (int i = 0; i < 2; i++) {
            gl_lds16(xhi + xsrc[i] + k0, (char*)Xhi_t + xdst[i]);
            gl_lds16(xlo + xsrc[i] + k0, (char*)Xlo_t + xdst[i]);
        }
        // stage G: fp32 load, hi/lo bf16 split, fused g2 accumulation
        f32x4 v0 = *(const f32x4*)(gp0 + k0);
        f32x4 v1 = *(const f32x4*)(gp0 + k0 + 4);
        short8 h8, l8;
        #pragma unroll
        for (int j = 0; j < 4; j++) {
            float a = v0[j], b = v1[j];
            unsigned short ha = f2bf(a), hb = f2bf(b);
            h8[j]     = (short)ha;  h8[j + 4] = (short)hb;
            l8[j]     = (short)f2bf(a - bf2f(ha));
            l8[j + 4] = (short)f2bf(b - bf2f(hb));
            g2acc += a * a + b * b;
        }
        *(short8*)&Ghi_t[gwr] = h8;
        *(short8*)&Glo_t[gwr] = l8;
        // emit bf16 copy of gt for drift (each element written exactly once)
        if (ng0 < N_SZ) *(short8*)(ghp0 + k0) = h8;

        __syncthreads();

        short8 bhi[2], blo[2];
        #pragma unroll
        for (int ni = 0; ni < 2; ni++) {
            int r = nh * 32 + ni * 16 + lm;
            int sl = r * 32 + swz(r, qd) * 8;
            bhi[ni] = *(short8*)&Ghi_t[sl];
            blo[ni] = *(short8*)&Glo_t[sl];
        }
        #pragma unroll
        for (int mi = 0; mi < 4; mi++) {
            int r = mh * 64 + mi * 16 + lm;
            int sl = r * 32 + swz(r, qd) * 8;
            short8 ahi = *(short8*)&Xhi_t[sl];
            short8 alo = *(short8*)&Xlo_t[sl];
            #pragma unroll
            for (int ni = 0; ni < 2; ni++) {
                acc[mi][ni] = __builtin_amdgcn_mfma_f32_16x16x32_bf16(ahi, bhi[ni], acc[mi][ni], 0, 0, 0);
                acc[mi][ni] = __builtin_amdgcn_mfma_f32_16x16x32_bf16(ahi, blo[ni], acc[mi][ni], 0, 0, 0);
                acc[mi][ni] = __builtin_amdgcn_mfma_f32_16x16x32_bf16(alo, bhi[ni], acc[mi][ni], 0, 0, 0);
            }
        }
        __syncthreads();
    }

    // g2 partial: reduce over the 4 k-quarter threads of each row, one atomic
    g2acc += __shfl_xor(g2acc, 1);
    g2acc += __shfl_xor(g2acc, 2);
    if (gq == 0 && ng0 < N_SZ) atomicAdd(&G2[ng0], g2acc);

    // epilogue: C/D layout col=lane&15, row=qd*4+i ; plain store of partial
    float* XGp = XG_part + (size_t)kc * BN;
    #pragma unroll
    for (int mi = 0; mi < 4; mi++) {
        #pragma unroll
        for (int ni = 0; ni < 2; ni++) {
            int ncol = nh * 32 + ni * 16 + lm;
            int ng = nbase + ncol;
            if (ng < N_SZ) {
                #pragma unroll
                for (int i = 0; i < 4; i++) {
                    int m = mh * 64 + mi * 16 + qd * 4 + i;
                    XGp[(size_t)m * NPAD + ng] = acc[mi][ni][i];
                }
            }
        }
    }
}

// ---------------- sum4max: XG = sum_kc XG_part[kc]; fused row-max ---------
// grid 2560 = 128 b * 20 chunks of 1024 -> each block lies inside one b row.
__global__ __launch_bounds__(256) void sum4max(
        const float* __restrict__ XG_part, const float* __restrict__ G2,
        const float* __restrict__ tarr, float* __restrict__ XG,
        unsigned* __restrict__ Mkey)
{
    const int tid = threadIdx.x;
    const int b = blockIdx.x / 20;
    const int i = (blockIdx.x * 256 + tid) * 4;
    __shared__ float wred[4];

    f32x4 s = (f32x4){0.f, 0.f, 0.f, 0.f};
    #pragma unroll
    for (int kc = 0; kc < KC_S; kc++)
        s += *(const f32x4*)(XG_part + (size_t)kc * BN + i);
    *(f32x4*)(XG + i) = s;

    float tt  = tarr[b] / 999.0f;
    float sig = 1.0f - tt;
    float inv = 1.0f / (sig * sig);
    float c1 = tt * inv, c2 = 0.5f * tt * tt * inv;
    int n = i - b * NPAD;

    float mx = -3.402823466e+38f;
    #pragma unroll
    for (int j = 0; j < 4; j++)
        if (n + j < N_SZ) mx = fmaxf(mx, c1 * s[j] - c2 * G2[n + j]);
    #pragma unroll
    for (int o = 32; o > 0; o >>= 1) mx = fmaxf(mx, __shfl_xor(mx, o));
    if ((tid & 63) == 0) wred[tid >> 6] = mx;
    __syncthreads();
    if (tid == 0) {
        mx = fmaxf(fmaxf(wred[0], wred[1]), fmaxf(wred[2], wred[3]));
        atomicMax(&Mkey[b], fkey_enc(mx));
    }
}

// ---------------- expk: P = bf16(exp(s - m)), L[b] += partial sum ----------
__global__ __launch_bounds__(256) void expk(
        const float* __restrict__ XG, const float* __restrict__ G2,
        const float* __restrict__ tarr, const unsigned* __restrict__ Mkey,
        unsigned short* __restrict__ P, float* __restrict__ L)
{
    const int b  = blockIdx.x >> 3;
    const int ch = blockIdx.x & 7;
    const int tid = threadIdx.x;
    float tt  = tarr[b] / 999.0f;
    float sig = 1.0f - tt;
    float inv = 1.0f / (sig * sig);
    float c1 = tt * inv, c2 = 0.5f * tt * tt * inv;
    float m = fkey_dec(Mkey[b]);
    const float* xg = XG + (size_t)b * NPAD;
    unsigned short* prow = P + (size_t)b * NPAD;
    __shared__ float wred[4];

    float sum = 0.f;
    int n0 = ch * 2560;
    for (int n = n0 + tid; n < n0 + 2560; n += 256) {
        float p = 0.f;
        if (n < N_SZ) { p = expf(c1 * xg[n] - c2 * G2[n] - m); sum += p; }
        prow[n] = f2bf(p);            // pad region -> exact 0
    }
    #pragma unroll
    for (int o = 32; o > 0; o >>= 1) sum += __shfl_xor(sum, o);
    if ((tid & 63) == 0) wred[tid >> 6] = sum;
    __syncthreads();
    if (tid == 0) atomicAdd(&L[b], wred[0] + wred[1] + wred[2] + wred[3]);
}

// ---------------- drift: Dacc_part[kc][b][d] = partial P.Gh (plain stores) -
// grid = 24 d-tiles * 20 K-chunks = 480 blocks; K-chunk 1024 (32 steps of 32).
// Gh is bf16 (written by scores): half the read bytes of fp32 gt, and the
// LDS transpose pack is 2 integer ORs instead of 2 v_cvt_pk + fp32 loads.
__global__ __launch_bounds__(256) void drift_kernel(
        const unsigned short* __restrict__ Gh,
        const unsigned short* __restrict__ P,
        float* __restrict__ Dacc_part)
{
    __shared__ __align__(16) unsigned short Pt[128 * 32];
    __shared__ __align__(16) unsigned short Gt[128 * 40];  // [d][k], 80B rows (64B + 16B pad)

    const int tid = threadIdx.x;
    const int nt = blockIdx.x % 24;
    const int kc = blockIdx.x / 24;
    const int dbase = nt * 128;

    const int lane = tid & 63;
    const int wave = tid >> 6;
    const int mh = wave & 1;
    const int dh = wave >> 1;
    const int lm = lane & 15;
    const int qd = lane >> 4;

    // G staging map: thread -> (d-group of 4 cols, k-group of 4 rows)
    const int dg = tid & 31;
    const int kq = tid >> 5;

    // P staging (global_load_lds, swizzled source like scores' X)
    int psrc[2], pdst[2];
    #pragma unroll
    for (int i = 0; i < 2; i++) {
        int o = (i * 256 + tid) * 16;
        int r = o >> 6;
        int j = (o >> 4) & 3;
        pdst[i] = o;
        psrc[i] = r * NPAD + kc * 1024 + swz(r, j) * 8;
    }

    f32x4 acc[4][4];
    #pragma unroll
    for (int i = 0; i < 4; i++)
        #pragma unroll
        for (int j = 0; j < 4; j++)
            acc[i][j] = (f32x4){0.f, 0.f, 0.f, 0.f};

    for (int s = 0; s < 32; s++) {
        int kb = kc * 1024 + s * 32;
        // stage P tile (128 x 32 bf16) direct to LDS
        #pragma unroll
        for (int i = 0; i < 2; i++)
            gl_lds16(P + psrc[i] + s * 32, (char*)Pt + pdst[i]);
        // stage G transposed: global [k][d] bf16 -> LDS [d][k] bf16
        u16x4 row[4];
        #pragma unroll
        for (int i = 0; i < 4; i++) {
            int kg = kb + kq * 4 + i;
            if (kg > N_SZ - 1) kg = N_SZ - 1;   // clamp; P=0 there so product is 0
            row[i] = *(const u16x4*)(Gh + (size_t)kg * D_SZ + dbase + dg * 4);
        }
        #pragma unroll
        for (int j = 0; j < 4; j++) {
            unsigned u01 = (unsigned)row[0][j] | ((unsigned)row[1][j] << 16);
            unsigned u23 = (unsigned)row[2][j] | ((unsigned)row[3][j] << 16);
            uint2v pk = (uint2v){u01, u23};
            __builtin_memcpy((char*)Gt + (size_t)(dg * 4 + j) * 80 + kq * 8, &pk, 8);
        }
        __syncthreads();

        short8 af[4], bf8[4];
        #pragma unroll
        for (int mi = 0; mi < 4; mi++) {
            int r = mh * 64 + mi * 16 + lm;
            af[mi] = *(short8*)&Pt[r * 32 + swz(r, qd) * 8];
        }
        #pragma unroll
        for (int ni = 0; ni < 4; ni++)
            bf8[ni] = *(short8*)((char*)Gt + (size_t)(dh * 64 + ni * 16 + lm) * 80 + qd * 16);
        #pragma unroll
        for (int mi = 0; mi < 4; mi++)
            #pragma unroll
            for (int ni = 0; ni < 4; ni++)
                acc[mi][ni] = __builtin_amdgcn_mfma_f32_16x16x32_bf16(af[mi], bf8[ni], acc[mi][ni], 0, 0, 0);
        __syncthreads();
    }

    float* Dp = Dacc_part + (size_t)kc * BD;
    #pragma unroll
    for (int mi = 0; mi < 4; mi++)
        #pragma unroll
        for (int ni = 0; ni < 4; ni++) {
            int d = dbase + dh * 64 + ni * 16 + lm;
            #pragma unroll
            for (int i = 0; i < 4; i++) {
                int m = mh * 64 + mi * 16 + qd * 4 + i;
                Dp[(size_t)m * D_SZ + d] = acc[mi][ni][i];
            }
        }
}

// ---------------- epilogue: out = (sum_kc Dacc_part / L - x)/sig ----------
__global__ __launch_bounds__(256) void epilogue_kernel(
        const float* __restrict__ Dacc_part, const float* __restrict__ L,
        const float* __restrict__ x, const float* __restrict__ tarr,
        float* __restrict__ out)
{
    int i = (blockIdx.x * 256 + threadIdx.x) * 4;   // grid 384: covers BD
    int b = i / D_SZ;
    f32x4 s = (f32x4){0.f, 0.f, 0.f, 0.f};
    #pragma unroll
    for (int kc = 0; kc < KC_D; kc++)
        s += *(const f32x4*)(Dacc_part + (size_t)kc * BD + i);
    float tt = tarr[b] / 999.0f;
    float sig = 1.0f - tt;
    float invL = 1.0f / L[b];
    f32x4 xv = *(const f32x4*)(x + i);
    f32x4 o;
    #pragma unroll
    for (int j = 0; j < 4; j++) o[j] = (s[j] * invL - xv[j]) / sig;
    *(f32x4*)(out + i) = o;
}

extern "C" void kernel_launch(void* const* d_in, const int* in_sizes, int n_in,
                              void* d_out, int out_size, void* d_ws, size_t ws_size,
                              hipStream_t stream)
{
    const float* xt = (const float*)d_in[0];   // [128,3,32,32]
    const float* t  = (const float*)d_in[1];   // [128]
    const float* gt = (const float*)d_in[2];   // [20000,3,32,32]
    float* out = (float*)d_out;

    char* ws = (char*)d_ws;
    float*          XG_part  = (float*)(ws + 0);            // 4*BN*4   = 41943040
    float*          XG       = (float*)(ws + 41943040);     // BN*4     = 10485760
    float*          Dacc_part= (float*)(ws + 52428800);     // 20*BD*4  = 31457280
    float*          G2       = (float*)(ws + 83886080);     // 81920  } zeroed
    unsigned*       Mkey     = (unsigned*)(ws + 83968000);  //   512  } contiguous
    float*          L        = (float*)(ws + 83968512);     //   512  } 20736 f32
    unsigned short* Xhi      = (unsigned short*)(ws + 83969024);  // 786432
    unsigned short* Xlo      = (unsigned short*)(ws + 84755456);  // 786432
    unsigned short* P        = (unsigned short*)(ws + 85541888);  // 5242880
    unsigned short* Gh       = (unsigned short*)(ws + 90784768);  // 122880000
    // total ~204 MB (< ws poison size 983 MB)

    zero_small    <<<   81, 256, 0, stream>>>(G2);           // G2+Mkey+L
    prep_x        <<< 1536, 256, 0, stream>>>(xt, Xhi, Xlo);
    scores_kernel <<< 1252, 256, 0, stream>>>(gt, Xhi, Xlo, XG_part, G2, Gh);
    sum4max       <<< 2560, 256, 0, stream>>>(XG_part, G2, t, XG, Mkey);
    expk          <<< 1024, 256, 0, stream>>>(XG, G2, t, Mkey, P, L);
    drift_kernel  <<<  480, 256, 0, stream>>>(Gh, P, Dacc_part);
    epilogue_kernel<<< 384, 256, 0, stream>>>(Dacc_part, L, xt, t, out);
}

// Round 3
// 495.296 us; speedup vs baseline: 1.0061x; 1.0061x over previous
//
#include <hip/hip_runtime.h>
#include <hip/hip_bf16.h>
#include <stdint.h>

#define B_SZ   128
#define D_SZ   3072
#define N_SZ   20000
#define NPAD   20480   // 313*64 score tiles (20032) < NPAD; 40 drift K-chunks * 512
#define BN     (B_SZ * NPAD)     // 2621440 elems
#define BD     (B_SZ * D_SZ)     // 393216 elems
#define KC_S   4                 // scores K-chunks (768 each)
#define KC_D   40                // drift K-chunks (512 each)

typedef __attribute__((ext_vector_type(8))) short          short8;
typedef __attribute__((ext_vector_type(4))) float          f32x4;
typedef __attribute__((ext_vector_type(4))) unsigned short u16x4;
typedef __attribute__((ext_vector_type(2))) unsigned int   uint2v;

__device__ __forceinline__ unsigned short f2bf(float f) {
    unsigned u = __float_as_uint(f);
    u += 0x7FFFu + ((u >> 16) & 1u);   // round-to-nearest-even
    return (unsigned short)(u >> 16);
}
__device__ __forceinline__ float bf2f(unsigned short h) {
    return __uint_as_float(((unsigned)h) << 16);
}
// order-preserving float<->uint key for atomicMax over signed floats
__device__ __forceinline__ unsigned fkey_enc(float f) {
    unsigned b = __float_as_uint(f);
    return (b & 0x80000000u) ? ~b : (b | 0x80000000u);
}
__device__ __forceinline__ float fkey_dec(unsigned u) {
    return __uint_as_float((u & 0x80000000u) ? (u ^ 0x80000000u) : ~u);
}

__device__ __forceinline__ void gl_lds16(const void* g, void* l) {
    __builtin_amdgcn_global_load_lds(
        (const __attribute__((address_space(1))) void*)g,
        (__attribute__((address_space(3))) void*)l, 16, 0, 0);
}

// bank swizzle: 16B slot for (row r, k-quarter q) is q ^ ((r>>1)&3) -> 2-way
// aliasing only (free, m136); permutes within a 64B row so global coalescing
// of the staging loads is unchanged.
__device__ __forceinline__ int swz(int r, int q) { return q ^ ((r >> 1) & 3); }

// ---------------- zero G2 + Mkey + L (20736 floats, contiguous) ------------
__global__ __launch_bounds__(256) void zero_small(float* __restrict__ p)
{
    p[blockIdx.x * 256 + threadIdx.x] = 0.f;   // grid 81: 81*256 = 20736
}

// ---------------- split x into bf16 hi/lo ----------------
__global__ __launch_bounds__(256) void prep_x(const float* __restrict__ x,
                                              unsigned short* __restrict__ xhi,
                                              unsigned short* __restrict__ xlo)
{
    int i = blockIdx.x * 256 + threadIdx.x;     // exactly 128*3072
    float v = x[i];
    unsigned short h = f2bf(v);
    xhi[i] = h;
    xlo[i] = f2bf(v - bf2f(h));
}

// ---------------- scores: XG_part[kc][b][n] = partial x.g -----------------
// grid = 313 n-tiles * 4 K-chunks = 1252 blocks. Tile M=128 x N=64, K 768.
// Software-pipelined (2-phase, ONE barrier per 32-K step): issue next-step
// global loads before the MFMA phase, convert+LDS-write after it into the
// other buffer. Emits Gh = bf16(gt) for drift (each element written once);
// the Gh store is issued one step late from registers so its drain overlaps
// a full compute phase.
// split-precision: acc = xhi*ghi + xhi*glo + xlo*ghi  (fp32-accurate dot)
__global__ __launch_bounds__(256) void scores_kernel(
        const float* __restrict__ gt,
        const unsigned short* __restrict__ xhi,
        const unsigned short* __restrict__ xlo,
        float* __restrict__ XG_part,
        float* __restrict__ G2,
        unsigned short* __restrict__ Gh)
{
    __shared__ __align__(16) unsigned short Xhi_t[2][128 * 32];
    __shared__ __align__(16) unsigned short Xlo_t[2][128 * 32];
    __shared__ __align__(16) unsigned short Ghi_t[2][64 * 32];
    __shared__ __align__(16) unsigned short Glo_t[2][64 * 32];   // 48 KB total

    const int tid   = threadIdx.x;
    const int kc    = blockIdx.x & 3;        // K-chunk (4 x 768)
    const int nt    = blockIdx.x >> 2;       // n-tile (313)
    const int nbase = nt * 64;
    const int kcb   = kc * 768;

    const int lane = tid & 63;
    const int wave = tid >> 6;
    const int mh = wave & 1;      // M half (64 rows)
    const int nh = wave >> 1;     // N half (32 cols)
    const int lm = lane & 15;
    const int qd = lane >> 4;

    // G staging map: thread -> (row gn of 64, k-quarter gq of 4 -> 8 elems)
    const int gn = tid >> 2;
    const int gq = tid & 3;
    const int ng0 = nbase + gn;              // unclamped (for guards)
    int grow = ng0 > N_SZ - 1 ? N_SZ - 1 : ng0;
    const float* gp0 = gt + (size_t)grow * D_SZ + kcb + gq * 8;
    unsigned short* ghp0 = Gh + (size_t)ng0 * D_SZ + kcb + gq * 8;
    const int gwr = gn * 32 + swz(gn, gq) * 8;   // swizzled LDS slot (elems)

    // X staging (global_load_lds, lane-order dest): lane's implicit LDS slot
    // is (r = o>>6, j = (o>>4)&3); fetch the global k-group j^f(r) so readers
    // can use the same swizzle.
    int xsrc[2], xdst[2];
    #pragma unroll
    for (int i = 0; i < 2; i++) {
        int o = (i * 256 + tid) * 16;
        int r = o >> 6;
        int j = (o >> 4) & 3;
        xdst[i] = o;
        xsrc[i] = r * D_SZ + kcb + swz(r, j) * 8;
    }

    float g2acc = 0.0f;

    f32x4 acc[4][2];
    #pragma unroll
    for (int i = 0; i < 4; i++)
        #pragma unroll
        for (int j = 0; j < 2; j++)
            acc[i][j] = (f32x4){0.f, 0.f, 0.f, 0.f};

    // ---- prologue: stage step 0 into buffer 0 ----
    #pragma unroll
    for (int i = 0; i < 2; i++) {
        gl_lds16(xhi + xsrc[i], (char*)Xhi_t[0] + xdst[i]);
        gl_lds16(xlo + xsrc[i], (char*)Xlo_t[0] + xdst[i]);
    }
    f32x4 v0 = *(const f32x4*)(gp0);
    f32x4 v1 = *(const f32x4*)(gp0 + 4);
    short8 h8k, l8k;
    #pragma unroll
    for (int j = 0; j < 4; j++) {
        float a = v0[j], b = v1[j];
        unsigned short ha = f2bf(a), hb = f2bf(b);
        h8k[j]     = (short)ha;  h8k[j + 4] = (short)hb;
        l8k[j]     = (short)f2bf(a - bf2f(ha));
        l8k[j + 4] = (short)f2bf(b - bf2f(hb));
        g2acc += a * a + b * b;
    }
    *(short8*)&Ghi_t[0][gwr] = h8k;
    *(short8*)&Glo_t[0][gwr] = l8k;
    __syncthreads();

    #pragma unroll 2
    for (int t = 0; t < 24; t++) {
        const int buf = t & 1, nxt = buf ^ 1;
        // (A) deferred Gh store of THIS step's data; issue next-step loads
        if (ng0 < N_SZ) *(short8*)(ghp0 + t * 32) = h8k;
        if (t < 23) {
            #pragma unroll
            for (int i = 0; i < 2; i++) {
                gl_lds16(xhi + xsrc[i] + t * 32 + 32, (char*)Xhi_t[nxt] + xdst[i]);
                gl_lds16(xlo + xsrc[i] + t * 32 + 32, (char*)Xlo_t[nxt] + xdst[i]);
            }
            v0 = *(const f32x4*)(gp0 + t * 32 + 32);
            v1 = *(const f32x4*)(gp0 + t * 32 + 36);
        }
        // (B) compute on buf (loads above fly during this phase)
        short8 bhi[2], blo[2];
        #pragma unroll
        for (int ni = 0; ni < 2; ni++) {
            int r = nh * 32 + ni * 16 + lm;
            int sl = r * 32 + swz(r, qd) * 8;
            bhi[ni] = *(short8*)&Ghi_t[buf][sl];
            blo[ni] = *(short8*)&Glo_t[buf][sl];
        }
        #pragma unroll
        for (int mi = 0; mi < 4; mi++) {
            int r = mh * 64 + mi * 16 + lm;
            int sl = r * 32 + swz(r, qd) * 8;
            short8 ahi = *(short8*)&Xhi_t[buf][sl];
            short8 alo = *(short8*)&Xlo_t[buf][sl];
            #pragma unroll
            for (int ni = 0; ni < 2; ni++) {
                acc[mi][ni] = __builtin_amdgcn_mfma_f32_16x16x32_bf16(ahi, bhi[ni], acc[mi][ni], 0, 0, 0);
                acc[mi][ni] = __builtin_amdgcn_mfma_f32_16x16x32_bf16(ahi, blo[ni], acc[mi][ni], 0, 0, 0);
                acc[mi][ni] = __builtin_amdgcn_mfma_f32_16x16x32_bf16(alo, bhi[ni], acc[mi][ni], 0, 0, 0);
            }
        }
        // (C) convert next step's G (loads landed during MFMA) -> other buffer
        if (t < 23) {
            #pragma unroll
            for (int j = 0; j < 4; j++) {
                float a = v0[j], b = v1[j];
                unsigned short ha = f2bf(a), hb = f2bf(b);
                h8k[j]     = (short)ha;  h8k[j + 4] = (short)hb;
                l8k[j]     = (short)f2bf(a - bf2f(ha));
                l8k[j + 4] = (short)f2bf(b - bf2f(hb));
                g2acc += a * a + b * b;
            }
            *(short8*)&Ghi_t[nxt][gwr] = h8k;
            *(short8*)&Glo_t[nxt][gwr] = l8k;
        }
        __syncthreads();   // the ONLY barrier per K-step
    }

    // g2 partial: reduce over the 4 k-quarter threads of each row, one atomic
    g2acc += __shfl_xor(g2acc, 1);
    g2acc += __shfl_xor(g2acc, 2);
    if (gq == 0 && ng0 < N_SZ) atomicAdd(&G2[ng0], g2acc);

    // epilogue: C/D layout col=lane&15, row=qd*4+i ; plain store of partial
    float* XGp = XG_part + (size_t)kc * BN;
    #pragma unroll
    for (int mi = 0; mi < 4; mi++) {
        #pragma unroll
        for (int ni = 0; ni < 2; ni++) {
            int ncol = nh * 32 + ni * 16 + lm;
            int ng = nbase + ncol;
            if (ng < N_SZ) {
                #pragma unroll
                for (int i = 0; i < 4; i++) {
                    int m = mh * 64 + mi * 16 + qd * 4 + i;
                    XGp[(size_t)m * NPAD + ng] = acc[mi][ni][i];
                }
            }
        }
    }
}

// ---------------- sum4max: XG = sum_kc XG_part[kc]; fused row-max ---------
// grid 2560 = 128 b * 20 chunks of 1024 -> each block lies inside one b row.
__global__ __launch_bounds__(256) void sum4max(
        const float* __restrict__ XG_part, const float* __restrict__ G2,
        const float* __restrict__ tarr, float* __restrict__ XG,
        unsigned* __restrict__ Mkey)
{
    const int tid = threadIdx.x;
    const int b = blockIdx.x / 20;
    const int i = (blockIdx.x * 256 + tid) * 4;
    __shared__ float wred[4];

    f32x4 s = (f32x4){0.f, 0.f, 0.f, 0.f};
    #pragma unroll
    for (int kc = 0; kc < KC_S; kc++)
        s += *(const f32x4*)(XG_part + (size_t)kc * BN + i);
    *(f32x4*)(XG + i) = s;

    float tt  = tarr[b] / 999.0f;
    float sig = 1.0f - tt;
    float inv = 1.0f / (sig * sig);
    float c1 = tt * inv, c2 = 0.5f * tt * tt * inv;
    int n = i - b * NPAD;

    float mx = -3.402823466e+38f;
    #pragma unroll
    for (int j = 0; j < 4; j++)
        if (n + j < N_SZ) mx = fmaxf(mx, c1 * s[j] - c2 * G2[n + j]);
    #pragma unroll
    for (int o = 32; o > 0; o >>= 1) mx = fmaxf(mx, __shfl_xor(mx, o));
    if ((tid & 63) == 0) wred[tid >> 6] = mx;
    __syncthreads();
    if (tid == 0) {
        mx = fmaxf(fmaxf(wred[0], wred[1]), fmaxf(wred[2], wred[3]));
        atomicMax(&Mkey[b], fkey_enc(mx));
    }
}

// ---------------- expk: P = bf16(exp(s - m)), L[b] += partial sum ----------
__global__ __launch_bounds__(256) void expk(
        const float* __restrict__ XG, const float* __restrict__ G2,
        const float* __restrict__ tarr, const unsigned* __restrict__ Mkey,
        unsigned short* __restrict__ P, float* __restrict__ L)
{
    const int b  = blockIdx.x >> 3;
    const int ch = blockIdx.x & 7;
    const int tid = threadIdx.x;
    float tt  = tarr[b] / 999.0f;
    float sig = 1.0f - tt;
    float inv = 1.0f / (sig * sig);
    float c1 = tt * inv, c2 = 0.5f * tt * tt * inv;
    float m = fkey_dec(Mkey[b]);
    const float* xg = XG + (size_t)b * NPAD;
    unsigned short* prow = P + (size_t)b * NPAD;
    __shared__ float wred[4];

    float sum = 0.f;
    int n0 = ch * 2560;
    for (int n = n0 + tid; n < n0 + 2560; n += 256) {
        float p = 0.f;
        if (n < N_SZ) { p = expf(c1 * xg[n] - c2 * G2[n] - m); sum += p; }
        prow[n] = f2bf(p);            // pad region -> exact 0
    }
    #pragma unroll
    for (int o = 32; o > 0; o >>= 1) sum += __shfl_xor(sum, o);
    if ((tid & 63) == 0) wred[tid >> 6] = sum;
    __syncthreads();
    if (tid == 0) atomicAdd(&L[b], wred[0] + wred[1] + wred[2] + wred[3]);
}

// ---------------- drift: Dacc_part[kc][b][d] = partial P.Gh ----------------
// grid = 24 d-tiles * 40 K-chunks = 960 blocks (3.75/CU; KC_D=20's 480 was
// occupancy-starved at 1.9/CU); K-chunk 512 (16 steps of 32). Same 2-phase
// single-barrier pipeline as scores. Gh is bf16 (written by scores): half
// the read bytes of fp32 gt; pack is 2 integer ORs.
__global__ __launch_bounds__(256) void drift_kernel(
        const unsigned short* __restrict__ Gh,
        const unsigned short* __restrict__ P,
        float* __restrict__ Dacc_part)
{
    __shared__ __align__(16) unsigned short Pt[2][128 * 32];
    __shared__ __align__(16) unsigned short Gt[2][128 * 40];  // [d][k], 80B rows; 36 KB total

    const int tid = threadIdx.x;
    const int nt = blockIdx.x % 24;
    const int kc = blockIdx.x / 24;     // 0..39
    const int dbase = nt * 128;
    const int kcb = kc * 512;

    const int lane = tid & 63;
    const int wave = tid >> 6;
    const int mh = wave & 1;
    const int dh = wave >> 1;
    const int lm = lane & 15;
    const int qd = lane >> 4;

    // G staging map: thread -> (d-group of 4 cols, k-group of 4 rows)
    const int dg = tid & 31;
    const int kq = tid >> 5;

    // P staging (global_load_lds, swizzled source like scores' X)
    int psrc[2], pdst[2];
    #pragma unroll
    for (int i = 0; i < 2; i++) {
        int o = (i * 256 + tid) * 16;
        int r = o >> 6;
        int j = (o >> 4) & 3;
        pdst[i] = o;
        psrc[i] = r * NPAD + kcb + swz(r, j) * 8;
    }

    f32x4 acc[4][4];
    #pragma unroll
    for (int i = 0; i < 4; i++)
        #pragma unroll
        for (int j = 0; j < 4; j++)
            acc[i][j] = (f32x4){0.f, 0.f, 0.f, 0.f};

    const unsigned short* gbase = Gh + dbase + dg * 4;
    u16x4 row[4];

    // ---- prologue: stage step 0 into buffer 0 ----
    #pragma unroll
    for (int i = 0; i < 2; i++)
        gl_lds16(P + psrc[i], (char*)Pt[0] + pdst[i]);
    #pragma unroll
    for (int i = 0; i < 4; i++) {
        int kg = kcb + kq * 4 + i;
        if (kg > N_SZ - 1) kg = N_SZ - 1;   // clamp; P=0 there so product is 0
        row[i] = *(const u16x4*)(gbase + (size_t)kg * D_SZ);
    }
    #pragma unroll
    for (int j = 0; j < 4; j++) {
        unsigned u01 = (unsigned)row[0][j] | ((unsigned)row[1][j] << 16);
        unsigned u23 = (unsigned)row[2][j] | ((unsigned)row[3][j] << 16);
        uint2v pk = (uint2v){u01, u23};
        __builtin_memcpy((char*)Gt[0] + (size_t)(dg * 4 + j) * 80 + kq * 8, &pk, 8);
    }
    __syncthreads();

    #pragma unroll 2
    for (int s = 0; s < 16; s++) {
        const int buf = s & 1, nxt = buf ^ 1;
        // (A) issue next-step loads
        if (s < 15) {
            #pragma unroll
            for (int i = 0; i < 2; i++)
                gl_lds16(P + psrc[i] + (s + 1) * 32, (char*)Pt[nxt] + pdst[i]);
            #pragma unroll
            for (int i = 0; i < 4; i++) {
                int kg = kcb + (s + 1) * 32 + kq * 4 + i;
                if (kg > N_SZ - 1) kg = N_SZ - 1;
                row[i] = *(const u16x4*)(gbase + (size_t)kg * D_SZ);
            }
        }
        // (B) compute on buf
        short8 af[4], bf8[4];
        #pragma unroll
        for (int mi = 0; mi < 4; mi++) {
            int r = mh * 64 + mi * 16 + lm;
            af[mi] = *(short8*)&Pt[buf][r * 32 + swz(r, qd) * 8];
        }
        #pragma unroll
        for (int ni = 0; ni < 4; ni++)
            bf8[ni] = *(short8*)((char*)Gt[buf] + (size_t)(dh * 64 + ni * 16 + lm) * 80 + qd * 16);
        #pragma unroll
        for (int mi = 0; mi < 4; mi++)
            #pragma unroll
            for (int ni = 0; ni < 4; ni++)
                acc[mi][ni] = __builtin_amdgcn_mfma_f32_16x16x32_bf16(af[mi], bf8[ni], acc[mi][ni], 0, 0, 0);
        // (C) pack next step's G rows (landed during MFMA) -> other buffer
        if (s < 15) {
            #pragma unroll
            for (int j = 0; j < 4; j++) {
                unsigned u01 = (unsigned)row[0][j] | ((unsigned)row[1][j] << 16);
                unsigned u23 = (unsigned)row[2][j] | ((unsigned)row[3][j] << 16);
                uint2v pk = (uint2v){u01, u23};
                __builtin_memcpy((char*)Gt[nxt] + (size_t)(dg * 4 + j) * 80 + kq * 8, &pk, 8);
            }
        }
        __syncthreads();   // the ONLY barrier per K-step
    }

    float* Dp = Dacc_part + (size_t)kc * BD;
    #pragma unroll
    for (int mi = 0; mi < 4; mi++)
        #pragma unroll
        for (int ni = 0; ni < 4; ni++) {
            int d = dbase + dh * 64 + ni * 16 + lm;
            #pragma unroll
            for (int i = 0; i < 4; i++) {
                int m = mh * 64 + mi * 16 + qd * 4 + i;
                Dp[(size_t)m * D_SZ + d] = acc[mi][ni][i];
            }
        }
}

// ---------------- epilogue: out = (sum_kc Dacc_part / L - x)/sig ----------
__global__ __launch_bounds__(256) void epilogue_kernel(
        const float* __restrict__ Dacc_part, const float* __restrict__ L,
        const float* __restrict__ x, const float* __restrict__ tarr,
        float* __restrict__ out)
{
    int i = (blockIdx.x * 256 + threadIdx.x) * 4;   // grid 384: covers BD
    int b = i / D_SZ;
    f32x4 s = (f32x4){0.f, 0.f, 0.f, 0.f};
    #pragma unroll
    for (int kc = 0; kc < KC_D; kc++)
        s += *(const f32x4*)(Dacc_part + (size_t)kc * BD + i);
    float tt = tarr[b] / 999.0f;
    float sig = 1.0f - tt;
    float invL = 1.0f / L[b];
    f32x4 xv = *(const f32x4*)(x + i);
    f32x4 o;
    #pragma unroll
    for (int j = 0; j < 4; j++) o[j] = (s[j] * invL - xv[j]) / sig;
    *(f32x4*)(out + i) = o;
}

extern "C" void kernel_launch(void* const* d_in, const int* in_sizes, int n_in,
                              void* d_out, int out_size, void* d_ws, size_t ws_size,
                              hipStream_t stream)
{
    const float* xt = (const float*)d_in[0];   // [128,3,32,32]
    const float* t  = (const float*)d_in[1];   // [128]
    const float* gt = (const float*)d_in[2];   // [20000,3,32,32]
    float* out = (float*)d_out;

    char* ws = (char*)d_ws;
    float*          XG_part  = (float*)(ws + 0);             // 4*BN*4   = 41943040
    float*          XG       = (float*)(ws + 41943040);      // BN*4     = 10485760
    float*          Dacc_part= (float*)(ws + 52428800);      // 40*BD*4  = 62914560
    float*          G2       = (float*)(ws + 115343360);     // 81920  } zeroed
    unsigned*       Mkey     = (unsigned*)(ws + 115425280);  //   512  } contiguous
    float*          L        = (float*)(ws + 115425792);     //   512  } 20736 f32
    unsigned short* Xhi      = (unsigned short*)(ws + 115426304); // 786432
    unsigned short* Xlo      = (unsigned short*)(ws + 116212736); // 786432
    unsigned short* P        = (unsigned short*)(ws + 116999168); // 5242880
    unsigned short* Gh       = (unsigned short*)(ws + 122242048); // 122880000
    // total ~245 MB (< ws poison size 983 MB)

    zero_small    <<<   81, 256, 0, stream>>>(G2);           // G2+Mkey+L
    prep_x        <<< 1536, 256, 0, stream>>>(xt, Xhi, Xlo);
    scores_kernel <<< 1252, 256, 0, stream>>>(gt, Xhi, Xlo, XG_part, G2, Gh);
    sum4max       <<< 2560, 256, 0, stream>>>(XG_part, G2, t, XG, Mkey);
    expk          <<< 1024, 256, 0, stream>>>(XG, G2, t, Mkey, P, L);
    drift_kernel  <<<  960, 256, 0, stream>>>(Gh, P, Dacc_part);
    epilogue_kernel<<< 384, 256, 0, stream>>>(Dacc_part, L, xt, t, out);
}